// Round 5
// baseline (4793.536 us; speedup 1.0000x reference)
//
#include <hip/hip_runtime.h>
#include <stdint.h>

// CustomLoss: out[b] = MAE(all) + [mean(min_n d) + mean(min_b d)] + EMD1d(b)
// pred/target [32,1024,128] fp32 -> out 32 fp32.
//
// ws layout (total 72,351,744 B, unchanged):
//   colmin  u32[32768]     @ 0
//   pnorm   f32[32768]     @ 131072
//   tnorm   f32[32768]     @ 262144
//   emdP    f32[512]       @ 393216
//   maeP    f32[8192]      @ 395264
//   minbP   f32[256]       @ 428032
//   minb    u32[1M]        @ 1048576   (4MB; sort-phase aliases:)
//     hist/gdb u32[64][4][256] @ 1048576  (256KB)
//     status   u32[64][16][256]@ 1310720  (1MB)
//     tickets  u32[64]         @ 2359296
//   keysA   u32[64*131072] @ 5242880
//   keysB   u32[64*131072] @ 38797312

#define B_ 32
#define N_ 1024
#define D_ 128
#define SORTN_ (N_ * D_)
#define JOBS_ 64

#define OFF_COLMIN 0
#define OFF_PNORM  131072
#define OFF_TNORM  262144
#define OFF_EMDP   393216
#define OFF_MAEP   395264
#define OFF_MINBP  428032
#define OFF_MINB   1048576
#define OFF_HIST   1048576
#define OFF_STATUS 1310720
#define OFF_TICKET 2359296
#define OFF_KEYSA  5242880
#define OFF_KEYSB  38797312

#define AGG_FLAG 0x40000000u
#define CNT_MASK 0x3FFFFFFFu

__device__ __forceinline__ unsigned f2k(float f) {
    unsigned u = __float_as_uint(f);
    return (u & 0x80000000u) ? ~u : (u | 0x80000000u);
}
__device__ __forceinline__ float k2f(unsigned k) {
    unsigned u = (k & 0x80000000u) ? (k & 0x7FFFFFFFu) : ~k;
    return __uint_as_float(u);
}

// ---------------- generic zero ----------------
__global__ __launch_bounds__(256) void k_memz(unsigned* __restrict__ p, int n) {
    for (int i = blockIdx.x * 256 + threadIdx.x; i < n; i += gridDim.x * 256)
        p[i] = 0u;
}

// ---------------- init: +inf the min buffers ----------------
__global__ __launch_bounds__(256) void k_init(unsigned* colmin, unsigned* minb) {
    int i = blockIdx.x * 256 + threadIdx.x;
    int stride = gridDim.x * 256;
    for (int j = i; j < B_ * N_; j += stride) colmin[j] = 0x7F800000u;
    for (int j = i; j < N_ * N_; j += stride) minb[j] = 0x7F800000u;
}

// ---------------- prep: MAE partials, row norms, sort keys ----------------
__global__ __launch_bounds__(256) void k_prep(const float* __restrict__ pred,
                                              const float* __restrict__ tgt,
                                              float* __restrict__ pnorm,
                                              float* __restrict__ tnorm,
                                              unsigned* __restrict__ keys,
                                              float* __restrict__ maeP) {
    __shared__ float red[4];
    int w = threadIdx.x >> 6, lane = threadIdx.x & 63;
    int row = blockIdx.x * 4 + w;
    const float2* p2 = (const float2*)(pred + (size_t)row * D_);
    const float2* t2 = (const float2*)(tgt + (size_t)row * D_);
    float2 p = p2[lane];
    float2 t = t2[lane];
    float mae = fabsf(p.x - t.x) + fabsf(p.y - t.y);
    float pn = p.x * p.x + p.y * p.y;
    float tn = t.x * t.x + t.y * t.y;
    int b = row >> 10, r1 = row & 1023;
    unsigned* kp = keys + (size_t)b * SORTN_ + r1 * D_ + lane * 2;
    kp[0] = f2k(p.x); kp[1] = f2k(p.y);
    unsigned* kt = keys + (size_t)(B_ + b) * SORTN_ + r1 * D_ + lane * 2;
    kt[0] = f2k(t.x); kt[1] = f2k(t.y);
    #pragma unroll
    for (int off = 32; off > 0; off >>= 1) {
        mae += __shfl_down(mae, off);
        pn  += __shfl_down(pn, off);
        tn  += __shfl_down(tn, off);
    }
    if (lane == 0) { pnorm[row] = pn; tnorm[row] = tn; red[w] = mae; }
    __syncthreads();
    if (threadIdx.x == 0) maeP[blockIdx.x] = red[0] + red[1] + red[2] + red[3];
}

// ---------------- chamfer: 8x4 register tile, BM=128 BN=64 BK=32 ----------------
// grid (16 m-tiles, 8 n-tiles, 8 bg), block 256 = 16x16. LDS ~32KB, VGPR~108 -> 4 blocks/CU.
#define XPAD 36
__global__ __launch_bounds__(256) void k_chamfer(const float* __restrict__ pred,
                                                 const float* __restrict__ tgt,
                                                 const float* __restrict__ pnorm,
                                                 const float* __restrict__ tnorm,
                                                 unsigned* __restrict__ colmin,
                                                 unsigned* __restrict__ minb) {
    __shared__ float Xs[128][XPAD];
    __shared__ float Ys[64][XPAD];
    __shared__ float colred[16][65];
    int m0 = blockIdx.x * 64, n0 = blockIdx.y * 128, bg = blockIdx.z;
    int tid = threadIdx.x, ty = tid >> 4, tx = tid & 15;

    float mreg[8][4];
    #pragma unroll
    for (int i = 0; i < 8; i++)
        #pragma unroll
        for (int j = 0; j < 4; j++) mreg[i][j] = 3.0e38f;

    for (int bi = 0; bi < 4; ++bi) {
        int b = bg * 4 + bi;
        float acc[8][4];
        #pragma unroll
        for (int i = 0; i < 8; i++)
            #pragma unroll
            for (int j = 0; j < 4; j++) acc[i][j] = 0.f;

        for (int kc0 = 0; kc0 < 128; kc0 += 32) {
            __syncthreads();
            #pragma unroll
            for (int l = 0; l < 4; l++) {
                int lin = l * 256 + tid;
                int row = lin >> 3, kq = lin & 7;
                *(float4*)&Xs[row][kq * 4] =
                    *(const float4*)&pred[((size_t)b * N_ + n0 + row) * D_ + kc0 + kq * 4];
            }
            #pragma unroll
            for (int l = 0; l < 2; l++) {
                int lin = l * 256 + tid;
                int row = lin >> 3, kq = lin & 7;
                *(float4*)&Ys[row][kq * 4] =
                    *(const float4*)&tgt[((size_t)b * N_ + m0 + row) * D_ + kc0 + kq * 4];
            }
            __syncthreads();
            #pragma unroll
            for (int kc = 0; kc < 8; ++kc) {
                float4 yf[4];
                #pragma unroll
                for (int j = 0; j < 4; j++) yf[j] = *(float4*)&Ys[tx + 16 * j][kc * 4];
                #pragma unroll
                for (int i = 0; i < 8; i++) {
                    float4 xf = *(float4*)&Xs[ty + 16 * i][kc * 4];
                    #pragma unroll
                    for (int j = 0; j < 4; j++) {
                        acc[i][j] += xf.x * yf[j].x + xf.y * yf[j].y
                                   + xf.z * yf[j].z + xf.w * yf[j].w;
                    }
                }
            }
        }

        float tn_[4];
        #pragma unroll
        for (int j = 0; j < 4; j++) tn_[j] = tnorm[(size_t)b * N_ + m0 + tx + 16 * j];
        float cmin[4] = {3.0e38f, 3.0e38f, 3.0e38f, 3.0e38f};
        #pragma unroll
        for (int i = 0; i < 8; i++) {
            float pn = pnorm[(size_t)b * N_ + n0 + ty + 16 * i];
            #pragma unroll
            for (int j = 0; j < 4; j++) {
                float sq = pn + tn_[j] - 2.0f * acc[i][j];
                float d = sqrtf(fmaxf(sq, 1e-12f));
                mreg[i][j] = fminf(mreg[i][j], d);
                cmin[j] = fminf(cmin[j], d);
            }
        }
        #pragma unroll
        for (int j = 0; j < 4; j++) colred[ty][tx + 16 * j] = cmin[j];
        __syncthreads();
        if (tid < 64) {
            float v = 3.0e38f;
            #pragma unroll
            for (int q = 0; q < 16; q++) v = fminf(v, colred[q][tid]);
            atomicMin(&colmin[(size_t)b * N_ + m0 + tid], __float_as_uint(v));
        }
    }
    #pragma unroll
    for (int i = 0; i < 8; i++)
        #pragma unroll
        for (int j = 0; j < 4; j++)
            atomicMin(&minb[(size_t)(n0 + ty + 16 * i) * N_ + m0 + tx + 16 * j],
                      __float_as_uint(mreg[i][j]));
}

// ---------------- reduce minb -> per-block partials ----------------
__global__ __launch_bounds__(256) void k_redminb(const unsigned* __restrict__ minb,
                                                 float* __restrict__ minbP) {
    __shared__ float red[4];
    float s = 0.f;
    for (int i = blockIdx.x * 256 + threadIdx.x; i < N_ * N_; i += 256 * 256)
        s += __uint_as_float(minb[i]);
    #pragma unroll
    for (int off = 32; off > 0; off >>= 1) s += __shfl_down(s, off);
    int w = threadIdx.x >> 6, lane = threadIdx.x & 63;
    if (lane == 0) red[w] = s;
    __syncthreads();
    if (threadIdx.x == 0) minbP[blockIdx.x] = red[0] + red[1] + red[2] + red[3];
}

// ======== onesweep radix: one hist over original data (all 4 shifts) ========
// hist[job][shift][digit] u32. Ballot-counted (skew-proof for exponent byte).
__global__ __launch_bounds__(256) void k_hist_all(const unsigned* __restrict__ keysA,
                                                  unsigned* __restrict__ hist) {
    __shared__ unsigned wh[4][1024];   // [wave][shift*256+digit] 16KB
    int cx = blockIdx.x, j = blockIdx.y, tid = threadIdx.x;
    int w = tid >> 6, lane = tid & 63;
    #pragma unroll
    for (int q = 0; q < 4; q++) wh[w][q * 256 + (tid & 255)] = 0u;  // each wave zeroes.. need full
    for (int q = tid; q < 4096; q += 256) ((unsigned*)wh)[q] = 0u;
    __syncthreads();
    const unsigned* seg = keysA + (size_t)j * SORTN_ + cx * 16384 + w * 4096;
    for (int i = 0; i < 64; i++) {
        unsigned key = seg[i * 64 + lane];
        #pragma unroll
        for (int s = 0; s < 4; s++) {
            unsigned d = (key >> (8 * s)) & 255u;
            unsigned long long m = ~0ull;
            #pragma unroll
            for (int bit = 0; bit < 8; bit++) {
                unsigned long long bm = __ballot((d >> bit) & 1u);
                m &= ((d >> bit) & 1u) ? bm : ~bm;
            }
            int leader = __ffsll((unsigned long long)m) - 1;
            if (lane == leader) atomicAdd(&wh[w][s * 256 + d], (unsigned)__popcll(m));
        }
    }
    __syncthreads();
    for (int q = tid; q < 1024; q += 256) {
        unsigned v = wh[0][q] + wh[1][q] + wh[2][q] + wh[3][q];
        if (v) atomicAdd(&hist[(size_t)j * 1024 + q], v);
    }
}

// exclusive scan per (job,shift) -> digit bases, in place
__global__ __launch_bounds__(256) void k_scan_all(unsigned* __restrict__ hist) {
    __shared__ unsigned partial[256];
    int s = blockIdx.x, j = blockIdx.y, tid = threadIdx.x;
    unsigned* h = hist + (size_t)j * 1024 + s * 256;
    unsigned v = h[tid];
    partial[tid] = v;
    __syncthreads();
    for (int off = 1; off < 256; off <<= 1) {
        unsigned add = (tid >= off) ? partial[tid - off] : 0u;
        __syncthreads();
        partial[tid] += add;
        __syncthreads();
    }
    h[tid] = partial[tid] - v;   // exclusive
}

// onesweep scatter: grid (8, 64); per-job ticket -> tile pair (2tp, 2tp+1).
// Per tile: ballot-rank (stable), publish aggregate, lookback-sum earlier tiles,
// LDS reorder, coalesced run copy-out.
__global__ __launch_bounds__(256) void k_scat1(const unsigned* __restrict__ src,
                                               unsigned* __restrict__ dst,
                                               const unsigned* __restrict__ gdb,
                                               unsigned* __restrict__ status,
                                               unsigned* __restrict__ ticket,
                                               int shift, int pass) {
    __shared__ unsigned wrun[4][256];
    __shared__ unsigned Lbase[256];
    __shared__ int shiftb[256];
    __shared__ unsigned partial[256];
    __shared__ unsigned sorted[8192];
    __shared__ unsigned bidS;
    int tid = threadIdx.x, w = tid >> 6, lane = tid & 63;
    int j = blockIdx.y;
    if (tid == 0)
        bidS = __hip_atomic_fetch_add(&ticket[j], 1u, __ATOMIC_RELAXED,
                                      __HIP_MEMORY_SCOPE_AGENT);
    __syncthreads();
    int tp = (int)bidS;
    unsigned long long ltm = (1ull << lane) - 1ull;

    for (int half = 0; half < 2; ++half) {
        int t = 2 * tp + half;
        #pragma unroll
        for (int q = 0; q < 4; q++) wrun[q][tid] = 0u;
        __syncthreads();

        const unsigned* seg = src + (size_t)j * SORTN_ + t * 8192 + w * 2048;
        unsigned k[32];
        unsigned rk[32];
        #pragma unroll
        for (int i = 0; i < 32; i++) {
            unsigned key = seg[i * 64 + lane];
            k[i] = key;
            unsigned d = (key >> shift) & 255u;
            unsigned long long m = ~0ull;
            #pragma unroll
            for (int bit = 0; bit < 8; bit++) {
                unsigned long long bm = __ballot((d >> bit) & 1u);
                m &= ((d >> bit) & 1u) ? bm : ~bm;
            }
            int rnk = __popcll(m & ltm);
            int leader = __ffsll((unsigned long long)m) - 1;
            int cnt = __popcll(m);
            unsigned base = 0;
            if (lane == leader) base = atomicAdd(&wrun[w][d], (unsigned)cnt);
            base = __shfl(base, leader);
            rk[i] = base + (unsigned)rnk;
        }
        __syncthreads();

        unsigned c0 = wrun[0][tid], c1 = wrun[1][tid], c2 = wrun[2][tid], c3 = wrun[3][tid];
        unsigned btot = c0 + c1 + c2 + c3;
        // publish this tile's aggregate ASAP (digit = tid)
        __hip_atomic_store(&status[((size_t)j * 16 + t) * 256 + tid],
                           AGG_FLAG | btot, __ATOMIC_RELEASE, __HIP_MEMORY_SCOPE_AGENT);
        wrun[0][tid] = 0u; wrun[1][tid] = c0;
        wrun[2][tid] = c0 + c1; wrun[3][tid] = c0 + c1 + c2;
        partial[tid] = btot;
        __syncthreads();
        for (int off = 1; off < 256; off <<= 1) {
            unsigned add = (tid >= off) ? partial[tid - off] : 0u;
            __syncthreads();
            partial[tid] += add;
            __syncthreads();
        }
        unsigned lb = partial[tid] - btot;
        Lbase[tid] = lb;
        // lookback: sum aggregates of tiles 0..t-1 for digit tid
        unsigned excl = 0;
        for (int t2 = 0; t2 < t; ++t2) {
            unsigned v;
            do {
                v = __hip_atomic_load(&status[((size_t)j * 16 + t2) * 256 + tid],
                                      __ATOMIC_ACQUIRE, __HIP_MEMORY_SCOPE_AGENT);
            } while (!(v & AGG_FLAG));
            excl += v & CNT_MASK;
        }
        shiftb[tid] = (int)(gdb[(size_t)j * 1024 + pass * 256 + tid] + excl) - (int)lb;
        __syncthreads();

        #pragma unroll
        for (int i = 0; i < 32; i++) {
            unsigned d = (k[i] >> shift) & 255u;
            unsigned lp = Lbase[d] + wrun[w][d] + rk[i];
            sorted[lp] = k[i];
        }
        __syncthreads();

        unsigned* dstj = dst + (size_t)j * SORTN_;
        #pragma unroll 4
        for (int it = 0; it < 32; it++) {
            int q = it * 256 + tid;
            unsigned key = sorted[q];
            unsigned d = (key >> shift) & 255u;
            dstj[shiftb[d] + q] = key;
        }
        __syncthreads();
    }
}

// ---------------- emd partials ----------------
__global__ __launch_bounds__(256) void k_emdp(const unsigned* __restrict__ keys,
                                              float* __restrict__ emdP) {
    __shared__ float red[4];
    int c = blockIdx.x, b = blockIdx.y;
    const unsigned* sp = keys + (size_t)b * SORTN_ + c * 8192;
    const unsigned* st = keys + (size_t)(B_ + b) * SORTN_ + c * 8192;
    float s = 0.f;
    for (int i = threadIdx.x; i < 8192; i += 256)
        s += fabsf(k2f(sp[i]) - k2f(st[i]));
    #pragma unroll
    for (int off = 32; off > 0; off >>= 1) s += __shfl_down(s, off);
    int w = threadIdx.x >> 6, lane = threadIdx.x & 63;
    if (lane == 0) red[w] = s;
    __syncthreads();
    if (threadIdx.x == 0) emdP[b * 16 + c] = red[0] + red[1] + red[2] + red[3];
}

// ---------------- finalize ----------------
__device__ __forceinline__ float block_reduce256(float v, float* red) {
    #pragma unroll
    for (int off = 32; off > 0; off >>= 1) v += __shfl_down(v, off);
    int w = threadIdx.x >> 6, lane = threadIdx.x & 63;
    __syncthreads();
    if (lane == 0) red[w] = v;
    __syncthreads();
    return red[0] + red[1] + red[2] + red[3];
}

__global__ __launch_bounds__(256) void k_final(const unsigned* __restrict__ colmin,
                                               const float* __restrict__ maeP,
                                               const float* __restrict__ minbP,
                                               const float* __restrict__ emdP,
                                               float* __restrict__ out) {
    __shared__ float red[4];
    int tid = threadIdx.x;
    float s1 = 0.f, s2 = 0.f, s3 = 0.f;
    for (int i = tid; i < B_ * N_; i += 256) s1 += __uint_as_float(colmin[i]);
    for (int i = tid; i < 8192; i += 256) s2 += maeP[i];
    for (int i = tid; i < 256; i += 256) s3 += minbP[i];
    float colmin_sum = block_reduce256(s1, red);
    float mae_sum    = block_reduce256(s2, red);
    float minb_sum   = block_reduce256(s3, red);
    if (tid < B_) {
        float e = 0.f;
        #pragma unroll
        for (int c = 0; c < 16; c++) e += emdP[tid * 16 + c];
        float mae  = mae_sum * (1.0f / 4194304.0f);
        float cham = colmin_sum * (1.0f / 32768.0f)
                   + minb_sum * (1.0f / 1048576.0f);
        out[tid] = mae + cham + e * (1.0f / 131072.0f);
    }
}

extern "C" void kernel_launch(void* const* d_in, const int* in_sizes, int n_in,
                              void* d_out, int out_size, void* d_ws, size_t ws_size,
                              hipStream_t stream) {
    const float* pred = (const float*)d_in[0];
    const float* tgt  = (const float*)d_in[1];
    float* out = (float*)d_out;
    char* ws = (char*)d_ws;

    unsigned* colmin = (unsigned*)(ws + OFF_COLMIN);
    float* pnorm     = (float*)(ws + OFF_PNORM);
    float* tnorm     = (float*)(ws + OFF_TNORM);
    float* emdP      = (float*)(ws + OFF_EMDP);
    float* maeP      = (float*)(ws + OFF_MAEP);
    float* minbP     = (float*)(ws + OFF_MINBP);
    unsigned* minb   = (unsigned*)(ws + OFF_MINB);
    unsigned* hist   = (unsigned*)(ws + OFF_HIST);    // aliases minb region
    unsigned* status = (unsigned*)(ws + OFF_STATUS);
    unsigned* ticket = (unsigned*)(ws + OFF_TICKET);
    unsigned* keysA  = (unsigned*)(ws + OFF_KEYSA);
    unsigned* keysB  = (unsigned*)(ws + OFF_KEYSB);

    // zero hist + status + tickets (contiguous: 65536 + 262144 + 64 u32)
    hipLaunchKernelGGL(k_memz, dim3(256), dim3(256), 0, stream, hist, 65536 + 262144 + 64);
    hipLaunchKernelGGL(k_prep, dim3(8192), dim3(256), 0, stream,
                       pred, tgt, pnorm, tnorm, keysA, maeP);
    hipLaunchKernelGGL(k_hist_all, dim3(8, JOBS_), dim3(256), 0, stream, keysA, hist);
    hipLaunchKernelGGL(k_scan_all, dim3(4, JOBS_), dim3(256), 0, stream, hist);

    unsigned* bufs[2] = {keysA, keysB};
    for (int pass = 0; pass < 4; ++pass) {
        if (pass > 0)   // fresh status + tickets (pass 0 covered by first memz)
            hipLaunchKernelGGL(k_memz, dim3(256), dim3(256), 0, stream,
                               status, 262144 + 64);
        hipLaunchKernelGGL(k_scat1, dim3(8, JOBS_), dim3(256), 0, stream,
                           bufs[pass & 1], bufs[(pass & 1) ^ 1], hist, status, ticket,
                           pass * 8, pass);
    }
    hipLaunchKernelGGL(k_emdp, dim3(16, B_), dim3(256), 0, stream, keysA, emdP);

    // sort-phase aliases dead -> init min buffers, chamfer
    hipLaunchKernelGGL(k_init, dim3(512), dim3(256), 0, stream, colmin, minb);
    hipLaunchKernelGGL(k_chamfer, dim3(16, 8, 8), dim3(256), 0, stream,
                       pred, tgt, pnorm, tnorm, colmin, minb);
    hipLaunchKernelGGL(k_redminb, dim3(256), dim3(256), 0, stream, minb, minbP);
    hipLaunchKernelGGL(k_final, dim3(1), dim3(256), 0, stream,
                       colmin, maeP, minbP, emdP, out);
}

// Round 6
// 765.892 us; speedup vs baseline: 6.2588x; 6.2588x over previous
//
#include <hip/hip_runtime.h>
#include <stdint.h>

// CustomLoss: out[b] = MAE(all) + [mean(min_n d) + mean(min_b d)] + EMD1d(b)
// pred/target [32,1024,128] fp32 -> out 32 fp32.
//
// ws layout (total 72,351,744 B, proven):
//   colmin  u32[32768]     @ 0
//   pnorm   f32[32768]     @ 131072
//   tnorm   f32[32768]     @ 262144
//   emdP    f32[512]       @ 393216
//   maeP    f32[8192]      @ 395264
//   minbP   f32[256]       @ 428032
//   minb    u32[1M]        @ 1048576  (4MB; hosts radix hist g_h[64][16384] u32=4MB first)
//   keysA   u32[64*131072] @ 5242880
//   keysB   u32[64*131072] @ 38797312

#define B_ 32
#define N_ 1024
#define D_ 128
#define SORTN_ (N_ * D_)
#define JOBS_ 64

#define OFF_COLMIN 0
#define OFF_PNORM  131072
#define OFF_TNORM  262144
#define OFF_EMDP   393216
#define OFF_MAEP   395264
#define OFF_MINBP  428032
#define OFF_MINB   1048576
#define OFF_HIST   1048576
#define OFF_KEYSA  5242880
#define OFF_KEYSB  38797312

__device__ __forceinline__ unsigned f2k(float f) {
    unsigned u = __float_as_uint(f);
    return (u & 0x80000000u) ? ~u : (u | 0x80000000u);
}
__device__ __forceinline__ float k2f(unsigned k) {
    unsigned u = (k & 0x80000000u) ? (k & 0x7FFFFFFFu) : ~k;
    return __uint_as_float(u);
}

// ---------------- init: +inf the min buffers (after radix frees hist) ----------------
__global__ __launch_bounds__(256) void k_init(unsigned* colmin, unsigned* minb) {
    int i = blockIdx.x * 256 + threadIdx.x;
    int stride = gridDim.x * 256;
    for (int j = i; j < B_ * N_; j += stride) colmin[j] = 0x7F800000u;
    for (int j = i; j < N_ * N_; j += stride) minb[j] = 0x7F800000u;
}

// ---------------- prep: MAE partials, row norms, sort keys ----------------
__global__ __launch_bounds__(256) void k_prep(const float* __restrict__ pred,
                                              const float* __restrict__ tgt,
                                              float* __restrict__ pnorm,
                                              float* __restrict__ tnorm,
                                              unsigned* __restrict__ keys,
                                              float* __restrict__ maeP) {
    __shared__ float red[4];
    int w = threadIdx.x >> 6, lane = threadIdx.x & 63;
    int row = blockIdx.x * 4 + w;
    const float2* p2 = (const float2*)(pred + (size_t)row * D_);
    const float2* t2 = (const float2*)(tgt + (size_t)row * D_);
    float2 p = p2[lane];
    float2 t = t2[lane];
    float mae = fabsf(p.x - t.x) + fabsf(p.y - t.y);
    float pn = p.x * p.x + p.y * p.y;
    float tn = t.x * t.x + t.y * t.y;
    int b = row >> 10, r1 = row & 1023;
    unsigned* kp = keys + (size_t)b * SORTN_ + r1 * D_ + lane * 2;
    kp[0] = f2k(p.x); kp[1] = f2k(p.y);
    unsigned* kt = keys + (size_t)(B_ + b) * SORTN_ + r1 * D_ + lane * 2;
    kt[0] = f2k(t.x); kt[1] = f2k(t.y);
    #pragma unroll
    for (int off = 32; off > 0; off >>= 1) {
        mae += __shfl_down(mae, off);
        pn  += __shfl_down(pn, off);
        tn  += __shfl_down(tn, off);
    }
    if (lane == 0) { pnorm[row] = pn; tnorm[row] = tn; red[w] = mae; }
    __syncthreads();
    if (threadIdx.x == 0) maeP[blockIdx.x] = red[0] + red[1] + red[2] + red[3];
}

// ---------------- chamfer: 8x4 register tile, BM=128 BN=64 BK=32 ----------------
// grid (16 m-tiles, 8 n-tiles, 8 bg), block 256 = 16x16. LDS ~32KB, VGPR~108 -> 4 blocks/CU.
#define XPAD 36
__global__ __launch_bounds__(256) void k_chamfer(const float* __restrict__ pred,
                                                 const float* __restrict__ tgt,
                                                 const float* __restrict__ pnorm,
                                                 const float* __restrict__ tnorm,
                                                 unsigned* __restrict__ colmin,
                                                 unsigned* __restrict__ minb) {
    __shared__ float Xs[128][XPAD];
    __shared__ float Ys[64][XPAD];
    __shared__ float colred[16][65];
    int m0 = blockIdx.x * 64, n0 = blockIdx.y * 128, bg = blockIdx.z;
    int tid = threadIdx.x, ty = tid >> 4, tx = tid & 15;

    float mreg[8][4];
    #pragma unroll
    for (int i = 0; i < 8; i++)
        #pragma unroll
        for (int j = 0; j < 4; j++) mreg[i][j] = 3.0e38f;

    for (int bi = 0; bi < 4; ++bi) {
        int b = bg * 4 + bi;
        float acc[8][4];
        #pragma unroll
        for (int i = 0; i < 8; i++)
            #pragma unroll
            for (int j = 0; j < 4; j++) acc[i][j] = 0.f;

        for (int kc0 = 0; kc0 < 128; kc0 += 32) {
            __syncthreads();
            #pragma unroll
            for (int l = 0; l < 4; l++) {
                int lin = l * 256 + tid;
                int row = lin >> 3, kq = lin & 7;
                *(float4*)&Xs[row][kq * 4] =
                    *(const float4*)&pred[((size_t)b * N_ + n0 + row) * D_ + kc0 + kq * 4];
            }
            #pragma unroll
            for (int l = 0; l < 2; l++) {
                int lin = l * 256 + tid;
                int row = lin >> 3, kq = lin & 7;
                *(float4*)&Ys[row][kq * 4] =
                    *(const float4*)&tgt[((size_t)b * N_ + m0 + row) * D_ + kc0 + kq * 4];
            }
            __syncthreads();
            #pragma unroll
            for (int kc = 0; kc < 8; ++kc) {
                float4 yf[4];
                #pragma unroll
                for (int j = 0; j < 4; j++) yf[j] = *(float4*)&Ys[tx + 16 * j][kc * 4];
                #pragma unroll
                for (int i = 0; i < 8; i++) {
                    float4 xf = *(float4*)&Xs[ty + 16 * i][kc * 4];
                    #pragma unroll
                    for (int j = 0; j < 4; j++) {
                        acc[i][j] += xf.x * yf[j].x + xf.y * yf[j].y
                                   + xf.z * yf[j].z + xf.w * yf[j].w;
                    }
                }
            }
        }

        float tn_[4];
        #pragma unroll
        for (int j = 0; j < 4; j++) tn_[j] = tnorm[(size_t)b * N_ + m0 + tx + 16 * j];
        float cmin[4] = {3.0e38f, 3.0e38f, 3.0e38f, 3.0e38f};
        #pragma unroll
        for (int i = 0; i < 8; i++) {
            float pn = pnorm[(size_t)b * N_ + n0 + ty + 16 * i];
            #pragma unroll
            for (int j = 0; j < 4; j++) {
                float sq = pn + tn_[j] - 2.0f * acc[i][j];
                float d = sqrtf(fmaxf(sq, 1e-12f));
                mreg[i][j] = fminf(mreg[i][j], d);
                cmin[j] = fminf(cmin[j], d);
            }
        }
        #pragma unroll
        for (int j = 0; j < 4; j++) colred[ty][tx + 16 * j] = cmin[j];
        __syncthreads();
        if (tid < 64) {
            float v = 3.0e38f;
            #pragma unroll
            for (int q = 0; q < 16; q++) v = fminf(v, colred[q][tid]);
            atomicMin(&colmin[(size_t)b * N_ + m0 + tid], __float_as_uint(v));
        }
    }
    #pragma unroll
    for (int i = 0; i < 8; i++)
        #pragma unroll
        for (int j = 0; j < 4; j++)
            atomicMin(&minb[(size_t)(n0 + ty + 16 * i) * N_ + m0 + tx + 16 * j],
                      __float_as_uint(mreg[i][j]));
}

// ---------------- reduce minb -> per-block partials ----------------
__global__ __launch_bounds__(256) void k_redminb(const unsigned* __restrict__ minb,
                                                 float* __restrict__ minbP) {
    __shared__ float red[4];
    float s = 0.f;
    for (int i = blockIdx.x * 256 + threadIdx.x; i < N_ * N_; i += 256 * 256)
        s += __uint_as_float(minb[i]);
    #pragma unroll
    for (int off = 32; off > 0; off >>= 1) s += __shfl_down(s, off);
    int w = threadIdx.x >> 6, lane = threadIdx.x & 63;
    if (lane == 0) red[w] = s;
    __syncthreads();
    if (threadIdx.x == 0) minbP[blockIdx.x] = red[0] + red[1] + red[2] + red[3];
}

// ======== radix sort (round-3 proven): 8-bit x 4 passes, 8192-key tiles ========
// hist layout: g_h[job][digit*64 + tile*4 + wave], 64*16384 u32 = 4MB.

__global__ __launch_bounds__(256) void k_rhist(const unsigned* __restrict__ src,
                                               unsigned* __restrict__ g_h, int shift) {
    __shared__ unsigned wh[4][256];
    int t = blockIdx.x, j = blockIdx.y, tid = threadIdx.x;
    int w = tid >> 6, lane = tid & 63;
    #pragma unroll
    for (int q = 0; q < 4; q++) wh[q][tid] = 0u;
    __syncthreads();
    const unsigned* seg = src + (size_t)j * SORTN_ + t * 8192 + w * 2048;
    #pragma unroll 4
    for (int i = 0; i < 32; i++) {
        unsigned d = (seg[i * 64 + lane] >> shift) & 255u;
        atomicAdd(&wh[w][d], 1u);
    }
    __syncthreads();
    #pragma unroll
    for (int q = 0; q < 4; q++)
        g_h[(size_t)j * 16384 + tid * 64 + t * 4 + q] = wh[q][tid];
}

__global__ __launch_bounds__(256) void k_rscan(unsigned* __restrict__ g_h) {
    __shared__ unsigned partial[256];
    int j = blockIdx.x, tid = threadIdx.x;
    unsigned* hj = g_h + (size_t)j * 16384;
    unsigned s = 0;
    #pragma unroll 8
    for (int q = 0; q < 64; q++) s += hj[tid * 64 + q];
    partial[tid] = s;
    __syncthreads();
    for (int off = 1; off < 256; off <<= 1) {
        unsigned add = (tid >= off) ? partial[tid - off] : 0u;
        __syncthreads();
        partial[tid] += add;
        __syncthreads();
    }
    unsigned run = partial[tid] - s;   // exclusive base for digit=tid
    #pragma unroll 8
    for (int q = 0; q < 64; q++) {
        unsigned c = hj[tid * 64 + q];
        hj[tid * 64 + q] = run;
        run += c;
    }
}

// stable scatter: ballot-rank within wave (deterministic), block-local LDS reorder,
// coalesced bin-run copy-out. LDS ~51KB -> 3 blocks/CU.
__global__ __launch_bounds__(256) void k_rscatter(const unsigned* __restrict__ src,
                                                  const unsigned* __restrict__ gbase,
                                                  unsigned* __restrict__ dst, int shift) {
    __shared__ unsigned wrun[4][256];
    __shared__ unsigned waveoff[4][256];
    __shared__ unsigned Lbase[256];
    __shared__ unsigned partial[256];
    __shared__ int shiftb[256];
    __shared__ unsigned sorted[8192];
    __shared__ unsigned char binb[8192];
    int t = blockIdx.x, j = blockIdx.y, tid = threadIdx.x;
    int w = tid >> 6, lane = tid & 63;
    #pragma unroll
    for (int q = 0; q < 4; q++) wrun[q][tid] = 0u;
    __syncthreads();

    const unsigned* seg = src + (size_t)j * SORTN_ + t * 8192 + w * 2048;
    unsigned k[32];
    unsigned rk[32];
    unsigned long long ltm = (1ull << lane) - 1ull;
    #pragma unroll
    for (int i = 0; i < 32; i++) {
        unsigned key = seg[i * 64 + lane];
        k[i] = key;
        unsigned d = (key >> shift) & 255u;
        unsigned long long m = ~0ull;
        #pragma unroll
        for (int bit = 0; bit < 8; bit++) {
            unsigned long long bm = __ballot((d >> bit) & 1u);
            m &= ((d >> bit) & 1u) ? bm : ~bm;
        }
        int rnk = __popcll(m & ltm);
        int leader = __ffsll((unsigned long long)m) - 1;
        int cnt = __popcll(m);
        unsigned base = 0;
        if (lane == leader) base = atomicAdd(&wrun[w][d], (unsigned)cnt);
        base = __shfl(base, leader);
        rk[i] = base + (unsigned)rnk;
    }
    __syncthreads();

    unsigned c0 = wrun[0][tid], c1 = wrun[1][tid], c2 = wrun[2][tid], c3 = wrun[3][tid];
    waveoff[0][tid] = 0u; waveoff[1][tid] = c0;
    waveoff[2][tid] = c0 + c1; waveoff[3][tid] = c0 + c1 + c2;
    unsigned btot = c0 + c1 + c2 + c3;
    partial[tid] = btot;
    __syncthreads();
    for (int off = 1; off < 256; off <<= 1) {
        unsigned add = (tid >= off) ? partial[tid - off] : 0u;
        __syncthreads();
        partial[tid] += add;
        __syncthreads();
    }
    unsigned lb = partial[tid] - btot;
    Lbase[tid] = lb;
    shiftb[tid] = (int)gbase[(size_t)j * 16384 + tid * 64 + t * 4] - (int)lb;
    __syncthreads();

    #pragma unroll
    for (int i = 0; i < 32; i++) {
        unsigned d = (k[i] >> shift) & 255u;
        unsigned lp = Lbase[d] + waveoff[w][d] + rk[i];
        sorted[lp] = k[i];
        binb[lp] = (unsigned char)d;
    }
    __syncthreads();

    unsigned* dstj = dst + (size_t)j * SORTN_;
    #pragma unroll 4
    for (int it = 0; it < 32; it++) {
        int q = it * 256 + tid;
        unsigned d = binb[q];
        dstj[shiftb[d] + q] = sorted[q];
    }
}

// ---------------- emd partials ----------------
__global__ __launch_bounds__(256) void k_emdp(const unsigned* __restrict__ keys,
                                              float* __restrict__ emdP) {
    __shared__ float red[4];
    int c = blockIdx.x, b = blockIdx.y;
    const unsigned* sp = keys + (size_t)b * SORTN_ + c * 8192;
    const unsigned* st = keys + (size_t)(B_ + b) * SORTN_ + c * 8192;
    float s = 0.f;
    for (int i = threadIdx.x; i < 8192; i += 256)
        s += fabsf(k2f(sp[i]) - k2f(st[i]));
    #pragma unroll
    for (int off = 32; off > 0; off >>= 1) s += __shfl_down(s, off);
    int w = threadIdx.x >> 6, lane = threadIdx.x & 63;
    if (lane == 0) red[w] = s;
    __syncthreads();
    if (threadIdx.x == 0) emdP[b * 16 + c] = red[0] + red[1] + red[2] + red[3];
}

// ---------------- finalize ----------------
__device__ __forceinline__ float block_reduce256(float v, float* red) {
    #pragma unroll
    for (int off = 32; off > 0; off >>= 1) v += __shfl_down(v, off);
    int w = threadIdx.x >> 6, lane = threadIdx.x & 63;
    __syncthreads();
    if (lane == 0) red[w] = v;
    __syncthreads();
    return red[0] + red[1] + red[2] + red[3];
}

__global__ __launch_bounds__(256) void k_final(const unsigned* __restrict__ colmin,
                                               const float* __restrict__ maeP,
                                               const float* __restrict__ minbP,
                                               const float* __restrict__ emdP,
                                               float* __restrict__ out) {
    __shared__ float red[4];
    int tid = threadIdx.x;
    float s1 = 0.f, s2 = 0.f, s3 = 0.f;
    for (int i = tid; i < B_ * N_; i += 256) s1 += __uint_as_float(colmin[i]);
    for (int i = tid; i < 8192; i += 256) s2 += maeP[i];
    for (int i = tid; i < 256; i += 256) s3 += minbP[i];
    float colmin_sum = block_reduce256(s1, red);
    float mae_sum    = block_reduce256(s2, red);
    float minb_sum   = block_reduce256(s3, red);
    if (tid < B_) {
        float e = 0.f;
        #pragma unroll
        for (int c = 0; c < 16; c++) e += emdP[tid * 16 + c];
        float mae  = mae_sum * (1.0f / 4194304.0f);
        float cham = colmin_sum * (1.0f / 32768.0f)
                   + minb_sum * (1.0f / 1048576.0f);
        out[tid] = mae + cham + e * (1.0f / 131072.0f);
    }
}

extern "C" void kernel_launch(void* const* d_in, const int* in_sizes, int n_in,
                              void* d_out, int out_size, void* d_ws, size_t ws_size,
                              hipStream_t stream) {
    const float* pred = (const float*)d_in[0];
    const float* tgt  = (const float*)d_in[1];
    float* out = (float*)d_out;
    char* ws = (char*)d_ws;

    unsigned* colmin = (unsigned*)(ws + OFF_COLMIN);
    float* pnorm     = (float*)(ws + OFF_PNORM);
    float* tnorm     = (float*)(ws + OFF_TNORM);
    float* emdP      = (float*)(ws + OFF_EMDP);
    float* maeP      = (float*)(ws + OFF_MAEP);
    float* minbP     = (float*)(ws + OFF_MINBP);
    unsigned* minb   = (unsigned*)(ws + OFF_MINB);
    unsigned* g_h    = (unsigned*)(ws + OFF_HIST);   // aliases minb (radix first)
    unsigned* keysA  = (unsigned*)(ws + OFF_KEYSA);
    unsigned* keysB  = (unsigned*)(ws + OFF_KEYSB);

    hipLaunchKernelGGL(k_prep, dim3(8192), dim3(256), 0, stream,
                       pred, tgt, pnorm, tnorm, keysA, maeP);

    // 4 LSD radix passes (keysA -> B -> A -> B -> A)
    unsigned* bufs[2] = {keysA, keysB};
    for (int pass = 0; pass < 4; ++pass) {
        unsigned* s = bufs[pass & 1];
        unsigned* d = bufs[(pass & 1) ^ 1];
        int shift = pass * 8;
        hipLaunchKernelGGL(k_rhist, dim3(16, JOBS_), dim3(256), 0, stream, s, g_h, shift);
        hipLaunchKernelGGL(k_rscan, dim3(JOBS_), dim3(256), 0, stream, g_h);
        hipLaunchKernelGGL(k_rscatter, dim3(16, JOBS_), dim3(256), 0, stream,
                           s, g_h, d, shift);
    }
    hipLaunchKernelGGL(k_emdp, dim3(16, B_), dim3(256), 0, stream, keysA, emdP);

    // hist region dead -> minb/colmin init, then chamfer
    hipLaunchKernelGGL(k_init, dim3(512), dim3(256), 0, stream, colmin, minb);
    hipLaunchKernelGGL(k_chamfer, dim3(16, 8, 8), dim3(256), 0, stream,
                       pred, tgt, pnorm, tnorm, colmin, minb);
    hipLaunchKernelGGL(k_redminb, dim3(256), dim3(256), 0, stream, minb, minbP);
    hipLaunchKernelGGL(k_final, dim3(1), dim3(256), 0, stream,
                       colmin, maeP, minbP, emdP, out);
}

// Round 7
// 628.573 us; speedup vs baseline: 7.6261x; 1.2185x over previous
//
#include <hip/hip_runtime.h>
#include <stdint.h>

// CustomLoss: out[b] = MAE(all) + [mean(min_n d) + mean(min_b d)] + EMD1d(b)
// pred/target [32,1024,128] fp32 -> out 32 fp32.
//
// ws layout (total 72,351,744 B, proven):
//   colmin  u32[32768]     @ 0
//   pnorm   f32[32768]     @ 131072
//   tnorm   f32[32768]     @ 262144
//   emdP    f32[512]       @ 393216
//   maeP    f32[8192]      @ 395264
//   minbP   f32[256]       @ 428032
//   minb    u32[1M]        @ 1048576  (4MB; hosts radix hist g_h[64][16384] u32=4MB first)
//   keysA   u32[64*131072] @ 5242880
//   keysB   u32[64*131072] @ 38797312

#define B_ 32
#define N_ 1024
#define D_ 128
#define SORTN_ (N_ * D_)
#define JOBS_ 64

#define OFF_COLMIN 0
#define OFF_PNORM  131072
#define OFF_TNORM  262144
#define OFF_EMDP   393216
#define OFF_MAEP   395264
#define OFF_MINBP  428032
#define OFF_MINB   1048576
#define OFF_HIST   1048576
#define OFF_KEYSA  5242880
#define OFF_KEYSB  38797312

__device__ __forceinline__ unsigned f2k(float f) {
    unsigned u = __float_as_uint(f);
    return (u & 0x80000000u) ? ~u : (u | 0x80000000u);
}
__device__ __forceinline__ float k2f(unsigned k) {
    unsigned u = (k & 0x80000000u) ? (k & 0x7FFFFFFFu) : ~k;
    return __uint_as_float(u);
}

// ---------------- init: +inf the min buffers (after radix frees hist) ----------------
__global__ __launch_bounds__(256) void k_init(unsigned* colmin, unsigned* minb) {
    int i = blockIdx.x * 256 + threadIdx.x;
    int stride = gridDim.x * 256;
    for (int j = i; j < B_ * N_; j += stride) colmin[j] = 0x7F800000u;
    for (int j = i; j < N_ * N_; j += stride) minb[j] = 0x7F800000u;
}

// ---------------- prep: MAE partials, row norms, sort keys ----------------
__global__ __launch_bounds__(256) void k_prep(const float* __restrict__ pred,
                                              const float* __restrict__ tgt,
                                              float* __restrict__ pnorm,
                                              float* __restrict__ tnorm,
                                              unsigned* __restrict__ keys,
                                              float* __restrict__ maeP) {
    __shared__ float red[4];
    int w = threadIdx.x >> 6, lane = threadIdx.x & 63;
    int row = blockIdx.x * 4 + w;
    const float2* p2 = (const float2*)(pred + (size_t)row * D_);
    const float2* t2 = (const float2*)(tgt + (size_t)row * D_);
    float2 p = p2[lane];
    float2 t = t2[lane];
    float mae = fabsf(p.x - t.x) + fabsf(p.y - t.y);
    float pn = p.x * p.x + p.y * p.y;
    float tn = t.x * t.x + t.y * t.y;
    int b = row >> 10, r1 = row & 1023;
    unsigned* kp = keys + (size_t)b * SORTN_ + r1 * D_ + lane * 2;
    kp[0] = f2k(p.x); kp[1] = f2k(p.y);
    unsigned* kt = keys + (size_t)(B_ + b) * SORTN_ + r1 * D_ + lane * 2;
    kt[0] = f2k(t.x); kt[1] = f2k(t.y);
    #pragma unroll
    for (int off = 32; off > 0; off >>= 1) {
        mae += __shfl_down(mae, off);
        pn  += __shfl_down(pn, off);
        tn  += __shfl_down(tn, off);
    }
    if (lane == 0) { pnorm[row] = pn; tnorm[row] = tn; red[w] = mae; }
    __syncthreads();
    if (threadIdx.x == 0) maeP[blockIdx.x] = red[0] + red[1] + red[2] + red[3];
}

// ---------------- chamfer: 8x4 register tile, BM=128 BN=64 BK=64 ----------------
// Round-4-proven inner structure (VGPR 108). LDS trimmed to 51KB by aliasing
// colred onto Xs (extra sync makes it safe) -> 3 blocks/CU = 12 waves/CU.
// grid (16 m-tiles, 8 n-tiles, 8 bg) = 1024 blocks, 4 batches each.
#define XPAD 68
__global__ __launch_bounds__(256, 3) void k_chamfer(const float* __restrict__ pred,
                                                    const float* __restrict__ tgt,
                                                    const float* __restrict__ pnorm,
                                                    const float* __restrict__ tnorm,
                                                    unsigned* __restrict__ colmin,
                                                    unsigned* __restrict__ minb) {
    __shared__ float smem[192 * XPAD];          // 52224 B
    float* Xs = smem;                           // [128][XPAD]
    float* Ys = smem + 128 * XPAD;              // [64][XPAD]
    float* colred = smem;                       // flat[1024], aliases Xs rows 0..15
    int m0 = blockIdx.x * 64, n0 = blockIdx.y * 128, bg = blockIdx.z;
    int tid = threadIdx.x, ty = tid >> 4, tx = tid & 15;

    float mreg[8][4];
    #pragma unroll
    for (int i = 0; i < 8; i++)
        #pragma unroll
        for (int j = 0; j < 4; j++) mreg[i][j] = 3.0e38f;

    #pragma unroll 1
    for (int bi = 0; bi < 4; ++bi) {
        int b = bg * 4 + bi;
        float acc[8][4];
        #pragma unroll
        for (int i = 0; i < 8; i++)
            #pragma unroll
            for (int j = 0; j < 4; j++) acc[i][j] = 0.f;

        #pragma unroll 1
        for (int kc0 = 0; kc0 < 128; kc0 += 64) {
            __syncthreads();
            #pragma unroll
            for (int l = 0; l < 8; l++) {
                int lin = l * 256 + tid;
                int row = lin >> 4, kq = lin & 15;
                *(float4*)&Xs[row * XPAD + kq * 4] =
                    *(const float4*)&pred[((size_t)b * N_ + n0 + row) * D_ + kc0 + kq * 4];
            }
            #pragma unroll
            for (int l = 0; l < 4; l++) {
                int lin = l * 256 + tid;
                int row = lin >> 4, kq = lin & 15;
                *(float4*)&Ys[row * XPAD + kq * 4] =
                    *(const float4*)&tgt[((size_t)b * N_ + m0 + row) * D_ + kc0 + kq * 4];
            }
            __syncthreads();
            #pragma unroll 4
            for (int kc = 0; kc < 16; ++kc) {
                float4 yf[4];
                #pragma unroll
                for (int j = 0; j < 4; j++) yf[j] = *(float4*)&Ys[(tx + 16 * j) * XPAD + kc * 4];
                #pragma unroll
                for (int i = 0; i < 8; i++) {
                    float4 xf = *(float4*)&Xs[(ty + 16 * i) * XPAD + kc * 4];
                    #pragma unroll
                    for (int j = 0; j < 4; j++) {
                        acc[i][j] += xf.x * yf[j].x + xf.y * yf[j].y
                                   + xf.z * yf[j].z + xf.w * yf[j].w;
                    }
                }
            }
        }

        float tn_[4];
        #pragma unroll
        for (int j = 0; j < 4; j++) tn_[j] = tnorm[(size_t)b * N_ + m0 + tx + 16 * j];
        float cmin[4] = {3.0e38f, 3.0e38f, 3.0e38f, 3.0e38f};
        #pragma unroll
        for (int i = 0; i < 8; i++) {
            float pn = pnorm[(size_t)b * N_ + n0 + ty + 16 * i];
            #pragma unroll
            for (int j = 0; j < 4; j++) {
                float sq = pn + tn_[j] - 2.0f * acc[i][j];
                float d = sqrtf(fmaxf(sq, 1e-12f));
                mreg[i][j] = fminf(mreg[i][j], d);
                cmin[j] = fminf(cmin[j], d);
            }
        }
        __syncthreads();   // all Xs reads done before colred (aliased) writes
        #pragma unroll
        for (int j = 0; j < 4; j++) colred[ty * 64 + tx + 16 * j] = cmin[j];
        __syncthreads();
        if (tid < 64) {
            float v = 3.0e38f;
            #pragma unroll
            for (int q = 0; q < 16; q++) v = fminf(v, colred[q * 64 + tid]);
            atomicMin(&colmin[(size_t)b * N_ + m0 + tid], __float_as_uint(v));
        }
        // kc0-top sync (next bi) protects colred readers vs restaging
    }
    #pragma unroll
    for (int i = 0; i < 8; i++)
        #pragma unroll
        for (int j = 0; j < 4; j++)
            atomicMin(&minb[(size_t)(n0 + ty + 16 * i) * N_ + m0 + tx + 16 * j],
                      __float_as_uint(mreg[i][j]));
}

// ---------------- reduce minb -> per-block partials ----------------
__global__ __launch_bounds__(256) void k_redminb(const unsigned* __restrict__ minb,
                                                 float* __restrict__ minbP) {
    __shared__ float red[4];
    float s = 0.f;
    for (int i = blockIdx.x * 256 + threadIdx.x; i < N_ * N_; i += 256 * 256)
        s += __uint_as_float(minb[i]);
    #pragma unroll
    for (int off = 32; off > 0; off >>= 1) s += __shfl_down(s, off);
    int w = threadIdx.x >> 6, lane = threadIdx.x & 63;
    if (lane == 0) red[w] = s;
    __syncthreads();
    if (threadIdx.x == 0) minbP[blockIdx.x] = red[0] + red[1] + red[2] + red[3];
}

// ======== radix sort (round-3 proven): 8-bit x 4 passes, 8192-key tiles ========
// hist layout: g_h[job][digit*64 + tile*4 + wave], 64*16384 u32 = 4MB.

__global__ __launch_bounds__(256) void k_rhist(const unsigned* __restrict__ src,
                                               unsigned* __restrict__ g_h, int shift) {
    __shared__ unsigned wh[4][256];
    int t = blockIdx.x, j = blockIdx.y, tid = threadIdx.x;
    int w = tid >> 6, lane = tid & 63;
    #pragma unroll
    for (int q = 0; q < 4; q++) wh[q][tid] = 0u;
    __syncthreads();
    const unsigned* seg = src + (size_t)j * SORTN_ + t * 8192 + w * 2048;
    #pragma unroll 4
    for (int i = 0; i < 32; i++) {
        unsigned d = (seg[i * 64 + lane] >> shift) & 255u;
        atomicAdd(&wh[w][d], 1u);
    }
    __syncthreads();
    #pragma unroll
    for (int q = 0; q < 4; q++)
        g_h[(size_t)j * 16384 + tid * 64 + t * 4 + q] = wh[q][tid];
}

__global__ __launch_bounds__(256) void k_rscan(unsigned* __restrict__ g_h) {
    __shared__ unsigned partial[256];
    int j = blockIdx.x, tid = threadIdx.x;
    unsigned* hj = g_h + (size_t)j * 16384;
    unsigned s = 0;
    #pragma unroll 8
    for (int q = 0; q < 64; q++) s += hj[tid * 64 + q];
    partial[tid] = s;
    __syncthreads();
    for (int off = 1; off < 256; off <<= 1) {
        unsigned add = (tid >= off) ? partial[tid - off] : 0u;
        __syncthreads();
        partial[tid] += add;
        __syncthreads();
    }
    unsigned run = partial[tid] - s;   // exclusive base for digit=tid
    #pragma unroll 8
    for (int q = 0; q < 64; q++) {
        unsigned c = hj[tid * 64 + q];
        hj[tid * 64 + q] = run;
        run += c;
    }
}

// stable scatter: ballot-rank within wave (deterministic), block-local LDS reorder,
// coalesced bin-run copy-out. LDS ~51KB -> 3 blocks/CU.
__global__ __launch_bounds__(256) void k_rscatter(const unsigned* __restrict__ src,
                                                  const unsigned* __restrict__ gbase,
                                                  unsigned* __restrict__ dst, int shift) {
    __shared__ unsigned wrun[4][256];
    __shared__ unsigned waveoff[4][256];
    __shared__ unsigned Lbase[256];
    __shared__ unsigned partial[256];
    __shared__ int shiftb[256];
    __shared__ unsigned sorted[8192];
    __shared__ unsigned char binb[8192];
    int t = blockIdx.x, j = blockIdx.y, tid = threadIdx.x;
    int w = tid >> 6, lane = tid & 63;
    #pragma unroll
    for (int q = 0; q < 4; q++) wrun[q][tid] = 0u;
    __syncthreads();

    const unsigned* seg = src + (size_t)j * SORTN_ + t * 8192 + w * 2048;
    unsigned k[32];
    unsigned rk[32];
    unsigned long long ltm = (1ull << lane) - 1ull;
    #pragma unroll
    for (int i = 0; i < 32; i++) {
        unsigned key = seg[i * 64 + lane];
        k[i] = key;
        unsigned d = (key >> shift) & 255u;
        unsigned long long m = ~0ull;
        #pragma unroll
        for (int bit = 0; bit < 8; bit++) {
            unsigned long long bm = __ballot((d >> bit) & 1u);
            m &= ((d >> bit) & 1u) ? bm : ~bm;
        }
        int rnk = __popcll(m & ltm);
        int leader = __ffsll((unsigned long long)m) - 1;
        int cnt = __popcll(m);
        unsigned base = 0;
        if (lane == leader) base = atomicAdd(&wrun[w][d], (unsigned)cnt);
        base = __shfl(base, leader);
        rk[i] = base + (unsigned)rnk;
    }
    __syncthreads();

    unsigned c0 = wrun[0][tid], c1 = wrun[1][tid], c2 = wrun[2][tid], c3 = wrun[3][tid];
    waveoff[0][tid] = 0u; waveoff[1][tid] = c0;
    waveoff[2][tid] = c0 + c1; waveoff[3][tid] = c0 + c1 + c2;
    unsigned btot = c0 + c1 + c2 + c3;
    partial[tid] = btot;
    __syncthreads();
    for (int off = 1; off < 256; off <<= 1) {
        unsigned add = (tid >= off) ? partial[tid - off] : 0u;
        __syncthreads();
        partial[tid] += add;
        __syncthreads();
    }
    unsigned lb = partial[tid] - btot;
    Lbase[tid] = lb;
    shiftb[tid] = (int)gbase[(size_t)j * 16384 + tid * 64 + t * 4] - (int)lb;
    __syncthreads();

    #pragma unroll
    for (int i = 0; i < 32; i++) {
        unsigned d = (k[i] >> shift) & 255u;
        unsigned lp = Lbase[d] + waveoff[w][d] + rk[i];
        sorted[lp] = k[i];
        binb[lp] = (unsigned char)d;
    }
    __syncthreads();

    unsigned* dstj = dst + (size_t)j * SORTN_;
    #pragma unroll 4
    for (int it = 0; it < 32; it++) {
        int q = it * 256 + tid;
        unsigned d = binb[q];
        dstj[shiftb[d] + q] = sorted[q];
    }
}

// ---------------- emd partials ----------------
__global__ __launch_bounds__(256) void k_emdp(const unsigned* __restrict__ keys,
                                              float* __restrict__ emdP) {
    __shared__ float red[4];
    int c = blockIdx.x, b = blockIdx.y;
    const unsigned* sp = keys + (size_t)b * SORTN_ + c * 8192;
    const unsigned* st = keys + (size_t)(B_ + b) * SORTN_ + c * 8192;
    float s = 0.f;
    for (int i = threadIdx.x; i < 8192; i += 256)
        s += fabsf(k2f(sp[i]) - k2f(st[i]));
    #pragma unroll
    for (int off = 32; off > 0; off >>= 1) s += __shfl_down(s, off);
    int w = threadIdx.x >> 6, lane = threadIdx.x & 63;
    if (lane == 0) red[w] = s;
    __syncthreads();
    if (threadIdx.x == 0) emdP[b * 16 + c] = red[0] + red[1] + red[2] + red[3];
}

// ---------------- finalize ----------------
__device__ __forceinline__ float block_reduce256(float v, float* red) {
    #pragma unroll
    for (int off = 32; off > 0; off >>= 1) v += __shfl_down(v, off);
    int w = threadIdx.x >> 6, lane = threadIdx.x & 63;
    __syncthreads();
    if (lane == 0) red[w] = v;
    __syncthreads();
    return red[0] + red[1] + red[2] + red[3];
}

__global__ __launch_bounds__(256) void k_final(const unsigned* __restrict__ colmin,
                                               const float* __restrict__ maeP,
                                               const float* __restrict__ minbP,
                                               const float* __restrict__ emdP,
                                               float* __restrict__ out) {
    __shared__ float red[4];
    int tid = threadIdx.x;
    float s1 = 0.f, s2 = 0.f, s3 = 0.f;
    for (int i = tid; i < B_ * N_; i += 256) s1 += __uint_as_float(colmin[i]);
    for (int i = tid; i < 8192; i += 256) s2 += maeP[i];
    for (int i = tid; i < 256; i += 256) s3 += minbP[i];
    float colmin_sum = block_reduce256(s1, red);
    float mae_sum    = block_reduce256(s2, red);
    float minb_sum   = block_reduce256(s3, red);
    if (tid < B_) {
        float e = 0.f;
        #pragma unroll
        for (int c = 0; c < 16; c++) e += emdP[tid * 16 + c];
        float mae  = mae_sum * (1.0f / 4194304.0f);
        float cham = colmin_sum * (1.0f / 32768.0f)
                   + minb_sum * (1.0f / 1048576.0f);
        out[tid] = mae + cham + e * (1.0f / 131072.0f);
    }
}

extern "C" void kernel_launch(void* const* d_in, const int* in_sizes, int n_in,
                              void* d_out, int out_size, void* d_ws, size_t ws_size,
                              hipStream_t stream) {
    const float* pred = (const float*)d_in[0];
    const float* tgt  = (const float*)d_in[1];
    float* out = (float*)d_out;
    char* ws = (char*)d_ws;

    unsigned* colmin = (unsigned*)(ws + OFF_COLMIN);
    float* pnorm     = (float*)(ws + OFF_PNORM);
    float* tnorm     = (float*)(ws + OFF_TNORM);
    float* emdP      = (float*)(ws + OFF_EMDP);
    float* maeP      = (float*)(ws + OFF_MAEP);
    float* minbP     = (float*)(ws + OFF_MINBP);
    unsigned* minb   = (unsigned*)(ws + OFF_MINB);
    unsigned* g_h    = (unsigned*)(ws + OFF_HIST);   // aliases minb (radix first)
    unsigned* keysA  = (unsigned*)(ws + OFF_KEYSA);
    unsigned* keysB  = (unsigned*)(ws + OFF_KEYSB);

    hipLaunchKernelGGL(k_prep, dim3(8192), dim3(256), 0, stream,
                       pred, tgt, pnorm, tnorm, keysA, maeP);

    // 4 LSD radix passes (keysA -> B -> A -> B -> A)
    unsigned* bufs[2] = {keysA, keysB};
    for (int pass = 0; pass < 4; ++pass) {
        unsigned* s = bufs[pass & 1];
        unsigned* d = bufs[(pass & 1) ^ 1];
        int shift = pass * 8;
        hipLaunchKernelGGL(k_rhist, dim3(16, JOBS_), dim3(256), 0, stream, s, g_h, shift);
        hipLaunchKernelGGL(k_rscan, dim3(JOBS_), dim3(256), 0, stream, g_h);
        hipLaunchKernelGGL(k_rscatter, dim3(16, JOBS_), dim3(256), 0, stream,
                           s, g_h, d, shift);
    }
    hipLaunchKernelGGL(k_emdp, dim3(16, B_), dim3(256), 0, stream, keysA, emdP);

    // hist region dead -> minb/colmin init, then chamfer
    hipLaunchKernelGGL(k_init, dim3(512), dim3(256), 0, stream, colmin, minb);
    hipLaunchKernelGGL(k_chamfer, dim3(16, 8, 8), dim3(256), 0, stream,
                       pred, tgt, pnorm, tnorm, colmin, minb);
    hipLaunchKernelGGL(k_redminb, dim3(256), dim3(256), 0, stream, minb, minbP);
    hipLaunchKernelGGL(k_final, dim3(1), dim3(256), 0, stream,
                       colmin, maeP, minbP, emdP, out);
}